// Round 3
// baseline (189.347 us; speedup 1.0000x reference)
//
#include <hip/hip_runtime.h>
#include <hip/hip_bf16.h>
#include <math.h>

#define D 256
#define KNB 32
#define NEG_SLOPE 0.2f

using bfrag = __attribute__((ext_vector_type(8))) short;   // 8 bf16 (4 VGPR)
using ffrag = __attribute__((ext_vector_type(4))) float;   // 4 f32 acc

__device__ __forceinline__ unsigned short f2bf(float x) {
    __hip_bfloat16 h = __float2bfloat16(x);
    return *reinterpret_cast<unsigned short*>(&h);
}
__device__ __forceinline__ float bf2f(unsigned short u) {
    return __uint_as_float((unsigned)u << 16);
}

// ---------------------------------------------------------------------------
// prep: blocks 0..63 convert W (f32 [256][256]) -> Wbf (bf16, same layout).
// block 64: w_src[f]=sum_o a_src[o]W[o][f], w_tgt likewise.
// ws layout (floats): [0..255]=w_src  [256..511]=w_tgt
//                     [512..33279]=Wbf (65536 bf16)
//                     [33280.. ]=agg_bf (N*256 bf16)
// ---------------------------------------------------------------------------
__global__ __launch_bounds__(256) void prep_kernel(
    const float* __restrict__ W, const float* __restrict__ a_src,
    const float* __restrict__ a_tgt, float* __restrict__ ws)
{
    int t = threadIdx.x;
    int b = blockIdx.x;
    if (b < 64) {
        const float4* w4 = reinterpret_cast<const float4*>(W);
        float4 v = w4[b * 256 + t];
        ushort4 u;
        u.x = f2bf(v.x); u.y = f2bf(v.y); u.z = f2bf(v.z); u.w = f2bf(v.w);
        reinterpret_cast<ushort4*>(ws + 512)[b * 256 + t] = u;
    } else {
        float as = 0.f, at = 0.f;
        for (int o = 0; o < D; ++o) {
            float w = W[o * D + t];
            as = fmaf(a_src[o], w, as);
            at = fmaf(a_tgt[o], w, at);
        }
        ws[t]     = as;   // w_src
        ws[D + t] = at;   // w_tgt
    }
}

// ---------------------------------------------------------------------------
// Fused scores_t + attention + aggregate. One block (256 thr) per node.
// Neighbor tile staged to LDS as bf16 (16 KB) -> 8 blocks/CU occupancy.
// Scores computed from the f32 values in-register during staging.
// ---------------------------------------------------------------------------
__global__ __launch_bounds__(256) void attn_agg_kernel(
    const float* __restrict__ nodes, const float* __restrict__ neighbors,
    const float* __restrict__ ws, unsigned short* __restrict__ aggbf, int N)
{
    __shared__ __align__(16) unsigned short sn[KNB][D];   // 16 KB bf16
    __shared__ float sp[KNB];

    int t = threadIdx.x;
    int n = blockIdx.x;
    int lane = t & 63, w = t >> 6;

    // per-thread w_src chunk (float4 col index == lane for every staged row)
    float4 wsv = reinterpret_cast<const float4*>(ws)[lane];

    // scores_t[n] = nodes[n,:] . w_tgt  (each wave computes the full dot)
    float4 nv  = reinterpret_cast<const float4*>(nodes + (size_t)n * D)[lane];
    float4 wtv = reinterpret_cast<const float4*>(ws + D)[lane];
    float st = nv.x * wtv.x + nv.y * wtv.y + nv.z * wtv.z + nv.w * wtv.w;
    #pragma unroll
    for (int o = 1; o < 64; o <<= 1) st += __shfl_xor(st, o);

    // stage 32x256 tile as bf16; fuse w_src dot-partials on the f32 data.
    // float4 idx v = i*256+t -> row k = i*4 + w, float4 col = lane
    const float4* g = reinterpret_cast<const float4*>(neighbors + (size_t)n * (KNB * D));
    float pk[8];
    #pragma unroll
    for (int i = 0; i < 8; ++i) {
        float4 x = g[i * 256 + t];
        ushort4 u;
        u.x = f2bf(x.x); u.y = f2bf(x.y); u.z = f2bf(x.z); u.w = f2bf(x.w);
        *reinterpret_cast<ushort4*>(&sn[i * 4 + w][lane * 4]) = u;
        pk[i] = x.x * wsv.x + x.y * wsv.y + x.z * wsv.z + x.w * wsv.w;
    }
    #pragma unroll
    for (int i = 0; i < 8; ++i) {
        #pragma unroll
        for (int o = 1; o < 64; o <<= 1) pk[i] += __shfl_xor(pk[i], o);
    }
    if (lane == 0) {
        #pragma unroll
        for (int i = 0; i < 8; ++i) {      // wave w owns k = i*4 + w
            float e = pk[i] + st;
            e = (e >= 0.f) ? e : NEG_SLOPE * e;
            sp[i * 4 + w] = __expf(e);
        }
    }
    __syncthreads();

    float sum = 0.f, acc = 0.f;
    #pragma unroll
    for (int k = 0; k < KNB; ++k) {
        float p = sp[k];                    // LDS broadcast
        sum += p;
        acc = fmaf(p, bf2f(sn[k][t]), acc); // contiguous bf16 column read
    }
    aggbf[(size_t)n * D + t] = f2bf(acc / (sum + 1e-16f));
}

// ---------------------------------------------------------------------------
// out = elu(agg_bf @ Wbf^T + bias), f32 out. One wave per block, 16 rows.
// mfma_f32_16x16x32_bf16: D lane l: row=(l>>4)*4+reg, col=l&15
// ---------------------------------------------------------------------------
__global__ __launch_bounds__(64) void out_gemm_kernel(
    const unsigned short* __restrict__ aggbf,
    const unsigned short* __restrict__ wbf,
    const float* __restrict__ bias, float* __restrict__ out, int N)
{
    int l = threadIdx.x;
    int m0 = blockIdx.x * 16;
    if (m0 >= N) return;
    int lr = l & 15, lk = l >> 4;

    ffrag acc[16];
    #pragma unroll
    for (int nf = 0; nf < 16; ++nf) acc[nf] = ffrag{0.f, 0.f, 0.f, 0.f};

    #pragma unroll
    for (int ks = 0; ks < 8; ++ks) {
        bfrag a = *reinterpret_cast<const bfrag*>(
            aggbf + (size_t)(m0 + lr) * D + ks * 32 + lk * 8);
        #pragma unroll
        for (int nf = 0; nf < 16; ++nf) {
            bfrag b = *reinterpret_cast<const bfrag*>(
                wbf + (size_t)(nf * 16 + lr) * D + ks * 32 + lk * 8);
            acc[nf] = __builtin_amdgcn_mfma_f32_16x16x32_bf16(a, b, acc[nf], 0, 0, 0);
        }
    }

    #pragma unroll
    for (int nf = 0; nf < 16; ++nf) {
        int col = nf * 16 + lr;
        float bv = bias[col];
        #pragma unroll
        for (int r = 0; r < 4; ++r) {
            int m = m0 + lk * 4 + r;
            float x = acc[nf][r] + bv;
            x = (x > 0.f) ? x : expm1f(x);
            out[(size_t)m * D + col] = x;
        }
    }
}

// ---------------------------------------------------------------------------
extern "C" void kernel_launch(void* const* d_in, const int* in_sizes, int n_in,
                              void* d_out, int out_size, void* d_ws, size_t ws_size,
                              hipStream_t stream) {
    const float* nodes     = (const float*)d_in[0];
    const float* neighbors = (const float*)d_in[1];
    const float* W         = (const float*)d_in[2];
    const float* a_src     = (const float*)d_in[3];
    const float* a_tgt     = (const float*)d_in[4];
    const float* bias      = (const float*)d_in[5];
    float* out = (float*)d_out;
    float* ws  = (float*)d_ws;

    int N = in_sizes[0] / D;                                 // 20000
    unsigned short* wbf   = (unsigned short*)(ws + 512);     // 65536 bf16
    unsigned short* aggbf = (unsigned short*)(ws + 33280);   // N*256 bf16

    hipLaunchKernelGGL(prep_kernel, dim3(65), dim3(256), 0, stream,
                       W, a_src, a_tgt, ws);
    hipLaunchKernelGGL(attn_agg_kernel, dim3(N), dim3(256), 0, stream,
                       nodes, neighbors, ws, aggbf, N);
    hipLaunchKernelGGL(out_gemm_kernel, dim3(N / 16), dim3(64), 0, stream,
                       aggbf, wbf, bias, out, N);
}